// Round 1
// 524.533 us; speedup vs baseline: 1.0367x; 1.0367x over previous
//
#include <hip/hip_runtime.h>
#include <hip/hip_bf16.h>

typedef __hip_bfloat16 bf16;
typedef float f32x4 __attribute__((ext_vector_type(4)));
typedef short bf16x8 __attribute__((ext_vector_type(8)));
typedef short s16x4 __attribute__((ext_vector_type(4)));

#define NB 32
#define NC 256
#define NHID 128
#define NQKV 384
#define SMSCALE 0.17677669529663687f  // 32^-0.5
#define PADA 264                      // shorts per LDS A-row (256 + 8 pad)

// fp32 -> bf16 round-to-nearest-even (finite inputs)
__device__ __forceinline__ short f2bf(float f) {
  union { float f; unsigned u; } v;
  v.f = f;
  return (short)((v.u + 0x7fffu + ((v.u >> 16) & 1u)) >> 16);
}

// ---------------- K0: weight prep: bf16 + transpose to K-contiguous ----------------
// wqt[n=384][k=256] <- w_qkv[k][n];  wot[c=256][k=128] <- w_out[k][c]
__global__ __launch_bounds__(256) void k_prep_w(const float* __restrict__ wqkv,
                                                const float* __restrict__ wout,
                                                short* __restrict__ wqt,
                                                short* __restrict__ wot) {
  int i = blockIdx.x * 256 + threadIdx.x;
  if (i < 98304) {
    int n = i >> 8, k = i & 255;
    wqt[i] = f2bf(wqkv[(size_t)k * NQKV + n]);
  }
  if (i < 32768) {
    int c = i >> 7, k = i & 127;
    wot[i] = f2bf(wout[(size_t)k * NC + c]);
  }
}

// ---------------- K1: qkv = x @ w_qkv via MFMA, LDS-staged A, fused k-softmax ----------------
// block: 512 threads (8 waves), 64 rows (one (b,d) slice), full N=384.
// wave w: m-half h=w>>2 (32 rows), N-strip (w&3)*96.
// A staged once in LDS as bf16; k-channels routed through LDS for fused channel-softmax.
__global__ __launch_bounds__(512) void k_gemm_qkv(const float* __restrict__ x,
                                                  const short* __restrict__ wqt,
                                                  float* __restrict__ qt,
                                                  float* __restrict__ kt,
                                                  float* __restrict__ vt) {
  __shared__ short As[64 * PADA];     // 33792 B; reused as Ks f32[64][132] after K-loop
  float* Ks = (float*)As;

  const int t = threadIdx.x;
  const int lane = t & 63;
  const int w = t >> 6;               // 0..7
  const int l15 = lane & 15;
  const int q = lane >> 4;            // 0..3
  const int h = w >> 2;               // m-half
  const int strip = (w & 3) * 96;
  const int rowBase = blockIdx.x * 64;
  const int b = rowBase >> 12;
  const int d = (rowBase >> 6) & 63;

  // stage x -> bf16 into LDS (coalesced: one 1KB row per wave-instruction)
  {
    const int r = w;                  // base row 0..7
    const int c = (t & 63) * 4;
#pragma unroll
    for (int it = 0; it < 8; ++it) {
      int row = it * 8 + r;
      float4 f = *(const float4*)(x + (size_t)(rowBase + row) * NC + c);
      s16x4 sv;
      sv[0] = f2bf(f.x); sv[1] = f2bf(f.y); sv[2] = f2bf(f.z); sv[3] = f2bf(f.w);
      *(s16x4*)(As + row * PADA + c) = sv;
    }
  }
  __syncthreads();

  f32x4 acc[2][6] = {};
  for (int ks = 0; ks < 8; ++ks) {
    const int k0 = ks * 32 + q * 8;
    bf16x8 afr[2];
#pragma unroll
    for (int mi = 0; mi < 2; ++mi)
      afr[mi] = *(const bf16x8*)(As + (h * 32 + mi * 16 + l15) * PADA + k0);
#pragma unroll
    for (int nj = 0; nj < 6; ++nj) {
      const int n = strip + nj * 16 + l15;
      bf16x8 bfr = *(const bf16x8*)(wqt + (size_t)n * 256 + k0);
#pragma unroll
      for (int mi = 0; mi < 2; ++mi)
        acc[mi][nj] = __builtin_amdgcn_mfma_f32_16x16x32_bf16(afr[mi], bfr, acc[mi][nj], 0, 0, 0);
    }
  }
  __syncthreads();  // all As reads complete before Ks overwrite

  // epilogue: C-frag col(l15)=channel, row(q*4+rg)=spatial. q,v -> global; k -> LDS.
#pragma unroll
  for (int mi = 0; mi < 2; ++mi) {
#pragma unroll
    for (int nj = 0; nj < 6; ++nj) {
      const int g = strip + nj * 16 + l15;          // qkv channel 0..383 (wave-uniform branch)
      const int n_sp = h * 32 + mi * 16 + q * 4;
      if (g < 128) {
        float4 v;
        v.x = acc[mi][nj][0]; v.y = acc[mi][nj][1]; v.z = acc[mi][nj][2]; v.w = acc[mi][nj][3];
        *(float4*)(qt + (((size_t)(b * 128 + g)) << 12) + (d << 6) + n_sp) = v;
      } else if (g < 256) {
        const int kc = g - 128;
#pragma unroll
        for (int rg = 0; rg < 4; ++rg)
          Ks[(n_sp + rg) * 132 + kc] = acc[mi][nj][rg];
      } else {
        float4 v;
        v.x = acc[mi][nj][0]; v.y = acc[mi][nj][1]; v.z = acc[mi][nj][2]; v.w = acc[mi][nj][3];
        *(float4*)(vt + (((size_t)(b * 128 + (g - 256))) << 12) + (d << 6) + n_sp) = v;
      }
    }
  }
  __syncthreads();

  // fused k-softmax over the 128-channel axis, one row per 8-lane group
  {
    const int r = t >> 3;             // 0..63
    const int c0 = (t & 7) * 16;
    float vals[16];
    float m = -1e30f;
#pragma unroll
    for (int i = 0; i < 16; ++i) {
      vals[i] = Ks[r * 132 + c0 + i];
      m = fmaxf(m, vals[i]);
    }
    m = fmaxf(m, __shfl_xor(m, 1, 64));
    m = fmaxf(m, __shfl_xor(m, 2, 64));
    m = fmaxf(m, __shfl_xor(m, 4, 64));
    float s = 0.f;
#pragma unroll
    for (int i = 0; i < 16; ++i) {
      vals[i] = __expf(vals[i] - m);
      s += vals[i];
    }
    s += __shfl_xor(s, 1, 64);
    s += __shfl_xor(s, 2, 64);
    s += __shfl_xor(s, 4, 64);
    const float rinv = 1.f / s;
#pragma unroll
    for (int i = 0; i < 16; ++i)
      Ks[r * 132 + c0 + i] = vals[i] * rinv;
  }
  __syncthreads();

  // coalesced copy-out of normalized k
  {
    const int n = t & 63;
    const int c0 = (t >> 6) * 16;
    const size_t obase = (((size_t)(b * 128)) << 12) + (d << 6) + n;
#pragma unroll
    for (int i = 0; i < 16; ++i)
      kt[obase + (((size_t)(c0 + i)) << 12)] = Ks[n * 132 + c0 + i];
  }
}

// ---------------- K3: per (b,ch): ctx = K V^T ; out = ctx^T softmax(Q)*scale ----------------
__global__ __launch_bounds__(256) void k_attn(const float* __restrict__ kt,
                                              const float* __restrict__ vt,
                                              const float* __restrict__ qt,
                                              float* __restrict__ at) {
  const int ch = blockIdx.x;
  const int b = blockIdx.y;
  __shared__ float S1[64 * 65];  // K, then ctx
  __shared__ float S2[64 * 65];  // V, then Q
  const int tx = threadIdx.x & 15, ty = threadIdx.x >> 4;
  const int t = threadIdx.x;
  const size_t base = ((size_t)(b * 128 + ch)) << 12;
#pragma unroll
  for (int i = 0; i < 4; ++i) {
    int e = i * 1024 + t * 4;
    int d = e >> 6, n = e & 63;
    float4 kv = *(const float4*)(kt + base + e);
    float4 vv = *(const float4*)(vt + base + e);
    S1[d * 65 + n] = kv.x; S1[d * 65 + n + 1] = kv.y; S1[d * 65 + n + 2] = kv.z; S1[d * 65 + n + 3] = kv.w;
    S2[d * 65 + n] = vv.x; S2[d * 65 + n + 1] = vv.y; S2[d * 65 + n + 2] = vv.z; S2[d * 65 + n + 3] = vv.w;
  }
  __syncthreads();
  float ctx[4][4] = {};
  for (int n = 0; n < 64; ++n) {
    float kv[4], vv[4];
#pragma unroll
    for (int i = 0; i < 4; ++i) kv[i] = S1[(ty * 4 + i) * 65 + n];
#pragma unroll
    for (int j = 0; j < 4; ++j) vv[j] = S2[(tx * 4 + j) * 65 + n];
#pragma unroll
    for (int i = 0; i < 4; ++i)
#pragma unroll
      for (int j = 0; j < 4; ++j) ctx[i][j] += kv[i] * vv[j];
  }
  __syncthreads();
#pragma unroll
  for (int i = 0; i < 4; ++i)
#pragma unroll
    for (int j = 0; j < 4; ++j) S1[(ty * 4 + i) * 65 + tx * 4 + j] = ctx[i][j];
#pragma unroll
  for (int i = 0; i < 4; ++i) {
    int e = i * 1024 + t * 4;
    int d = e >> 6, n = e & 63;
    float4 qv = *(const float4*)(qt + base + e);
    S2[d * 65 + n] = qv.x; S2[d * 65 + n + 1] = qv.y; S2[d * 65 + n + 2] = qv.z; S2[d * 65 + n + 3] = qv.w;
  }
  __syncthreads();
  {
    const int d = t >> 2, qq = t & 3;
    float vals[16];
    float m = -1e30f;
#pragma unroll
    for (int k = 0; k < 16; ++k) {
      vals[k] = S2[d * 65 + qq * 16 + k];
      m = fmaxf(m, vals[k]);
    }
    m = fmaxf(m, __shfl_xor(m, 1, 64));
    m = fmaxf(m, __shfl_xor(m, 2, 64));
    float s = 0.f;
#pragma unroll
    for (int k = 0; k < 16; ++k) {
      vals[k] = __expf(vals[k] - m);
      s += vals[k];
    }
    s += __shfl_xor(s, 1, 64);
    s += __shfl_xor(s, 2, 64);
    float r = SMSCALE / s;
#pragma unroll
    for (int k = 0; k < 16; ++k) S2[d * 65 + qq * 16 + k] = vals[k] * r;
  }
  __syncthreads();
  float o[4][4] = {};
  for (int d = 0; d < 64; ++d) {
    float cv[4], qv[4];
#pragma unroll
    for (int i = 0; i < 4; ++i) cv[i] = S1[d * 65 + ty * 4 + i];
#pragma unroll
    for (int j = 0; j < 4; ++j) qv[j] = S2[d * 65 + tx * 4 + j];
#pragma unroll
    for (int i = 0; i < 4; ++i)
#pragma unroll
      for (int j = 0; j < 4; ++j) o[i][j] += cv[i] * qv[j];
  }
#pragma unroll
  for (int i = 0; i < 4; ++i) {
    float4 v;
    v.x = o[i][0]; v.y = o[i][1]; v.z = o[i][2]; v.w = o[i][3];
    *(float4*)(at + base + (ty * 4 + i) * 64 + tx * 4) = v;
  }
}

// ---------------- K4: y = attn @ w_out + b_out via MFMA (XOR-swizzled LDS transpose of at) ----------------
__global__ __launch_bounds__(256) void k_gemm_out(const float* __restrict__ at,
                                                  const short* __restrict__ wot,
                                                  const float* __restrict__ bias,
                                                  float* __restrict__ y,
                                                  float* __restrict__ sums) {
  __shared__ short As[64 * 128];  // [m=r][k=ch], 16B-unit XOR swizzle: u_phys = u ^ (m&15)
  __shared__ float red[8];
  const int t = threadIdx.x;
  const int lane = t & 63;
  const int w = t >> 6;
  const int l15 = lane & 15;
  const int q = lane >> 4;
  const int rowBase = blockIdx.x * 64;
  const int b = rowBase >> 12;
  const int r0 = rowBase & 4095;
  const size_t abase = (((size_t)(b * 128)) << 12) + r0;
  // stage at[ch][r] -> As[r][ch] bf16 via 4x4 in-register transpose
  {
    const int tr = t & 15;   // r-tile: rows tr*4..tr*4+3
    const int tk = t >> 4;   // 0..15
#pragma unroll
    for (int i = 0; i < 2; ++i) {
      const int kq = tk + 16 * i;  // 0..31 -> k = kq*4 + kc
      float4 f[4];
#pragma unroll
      for (int kc = 0; kc < 4; ++kc)
        f[kc] = *(const float4*)(at + abase + (((size_t)(kq * 4 + kc)) << 12) + tr * 4);
      const int ul = kq >> 1, h = kq & 1;
#pragma unroll
      for (int j = 0; j < 4; ++j) {
        int m = tr * 4 + j;
        s16x4 sv;
        sv[0] = f2bf(f[0][j]); sv[1] = f2bf(f[1][j]); sv[2] = f2bf(f[2][j]); sv[3] = f2bf(f[3][j]);
        *(s16x4*)(As + m * 128 + ((ul ^ (m & 15)) << 3) + h * 4) = sv;
      }
    }
  }
  __syncthreads();
  f32x4 acc[4][4] = {};
  for (int ks = 0; ks < 4; ++ks) {
    bf16x8 afr[4];
#pragma unroll
    for (int mi = 0; mi < 4; ++mi) {
      int m = mi * 16 + l15;
      int ul = ks * 4 + q;
      afr[mi] = *(const bf16x8*)(As + m * 128 + ((ul ^ (m & 15)) << 3));
    }
#pragma unroll
    for (int nj = 0; nj < 4; ++nj) {
      int c = w * 64 + nj * 16 + l15;
      bf16x8 bfr = *(const bf16x8*)(wot + (size_t)c * 128 + ks * 32 + q * 8);
#pragma unroll
      for (int mi = 0; mi < 4; ++mi)
        acc[mi][nj] = __builtin_amdgcn_mfma_f32_16x16x32_bf16(afr[mi], bfr, acc[mi][nj], 0, 0, 0);
    }
  }
  // epilogue: bias, store, fused GN partial sums
  float ls = 0.f, lss = 0.f;
#pragma unroll
  for (int mi = 0; mi < 4; ++mi) {
    int r = rowBase + mi * 16 + q * 4;
#pragma unroll
    for (int nj = 0; nj < 4; ++nj) {
      int c = w * 64 + nj * 16 + l15;
      float bv = bias[c];
#pragma unroll
      for (int rg = 0; rg < 4; ++rg) {
        float v = acc[mi][nj][rg] + bv;
        y[(size_t)(r + rg) * NC + c] = v;
        ls += v;
        lss += v * v;
      }
    }
  }
#pragma unroll
  for (int off = 32; off; off >>= 1) {
    ls += __shfl_xor(ls, off, 64);
    lss += __shfl_xor(lss, off, 64);
  }
  if (lane == 0) {
    red[w] = ls;
    red[4 + w] = lss;
  }
  __syncthreads();
  if (t == 0) {
    float S = red[0] + red[1] + red[2] + red[3];
    float SS = red[4] + red[5] + red[6] + red[7];
    atomicAdd(&sums[2 * b], S);
    atomicAdd(&sums[2 * b + 1], SS);
  }
}

// ---------------- K5: GroupNorm(1 group) finalize, in place ----------------
__global__ __launch_bounds__(256) void k_gnorm(float* __restrict__ y,
                                               const float* __restrict__ sums,
                                               const float* __restrict__ gs,
                                               const float* __restrict__ gb) {
  size_t i0 = ((size_t)blockIdx.x * 256 + threadIdx.x) * 4;
  int b = (int)(i0 >> 20);
  int c = (int)(i0 & 255);
  const float invN = 1.0f / 1048576.0f;
  float mean = sums[2 * b] * invN;
  float var = sums[2 * b + 1] * invN - mean * mean;
  float inv = rsqrtf(var + 1e-6f);
  float4 v = *((const float4*)(y + i0));
  float4 g = *((const float4*)(gs + c));
  float4 bb = *((const float4*)(gb + c));
  float4 r;
  r.x = (v.x - mean) * inv * g.x + bb.x;
  r.y = (v.y - mean) * inv * g.y + bb.y;
  r.z = (v.z - mean) * inv * g.z + bb.z;
  r.w = (v.w - mean) * inv * g.w + bb.w;
  *((float4*)(y + i0)) = r;
}

extern "C" void kernel_launch(void* const* d_in, const int* in_sizes, int n_in,
                              void* d_out, int out_size, void* d_ws, size_t ws_size,
                              hipStream_t stream) {
  const float* x = (const float*)d_in[0];
  const float* w_qkv = (const float*)d_in[1];
  const float* w_out = (const float*)d_in[2];
  const float* b_out = (const float*)d_in[3];
  const float* gn_scale = (const float*)d_in[4];
  const float* gn_bias = (const float*)d_in[5];
  float* out = (float*)d_out;

  char* ws = (char*)d_ws;
  const size_t SLAB = (size_t)67108864;  // 64 MiB
  float* qt = (float*)ws;
  float* kt = (float*)(ws + SLAB);
  float* vt = (float*)(ws + 2 * SLAB);
  float* at = qt;  // alias: k_attn consumes its qt slice before writing its at slice
  float* sums = (float*)(ws + 3 * SLAB);
  short* wqt = (short*)(ws + 3 * SLAB + 1024);
  short* wot = (short*)(ws + 3 * SLAB + 1024 + 196608);

  hipMemsetAsync(sums, 0, 64 * sizeof(float), stream);

  k_prep_w<<<384, 256, 0, stream>>>(w_qkv, w_out, wqt, wot);
  k_gemm_qkv<<<2048, 512, 0, stream>>>(x, wqt, qt, kt, vt);
  k_attn<<<dim3(128, 32), 256, 0, stream>>>(kt, vt, qt, at);
  k_gemm_out<<<2048, 256, 0, stream>>>(at, wot, b_out, out, sums);
  k_gnorm<<<32768, 256, 0, stream>>>(out, sums, gn_scale, gn_bias);
}

// Round 2
// 429.817 us; speedup vs baseline: 1.2651x; 1.2204x over previous
//
#include <hip/hip_runtime.h>
#include <hip/hip_bf16.h>

typedef __hip_bfloat16 bf16;
typedef float f32x4 __attribute__((ext_vector_type(4)));
typedef short bf16x8 __attribute__((ext_vector_type(8)));
typedef short s16x4 __attribute__((ext_vector_type(4)));

#define NB 32
#define NC 256
#define NHID 128
#define NQKV 384
#define SMSCALE 0.17677669529663687f  // 32^-0.5
#define PADA 264                      // shorts per LDS A-row (256 + 8 pad)

// fp32 -> bf16 round-to-nearest-even (finite inputs)
__device__ __forceinline__ short f2bf(float f) {
  union { float f; unsigned u; } v;
  v.f = f;
  return (short)((v.u + 0x7fffu + ((v.u >> 16) & 1u)) >> 16);
}
__device__ __forceinline__ float bf2f(short s) {
  union { unsigned u; float f; } v;
  v.u = ((unsigned)(unsigned short)s) << 16;
  return v.f;
}

// ---------------- K0: weight prep: bf16 + transpose to K-contiguous ----------------
__global__ __launch_bounds__(256) void k_prep_w(const float* __restrict__ wqkv,
                                                const float* __restrict__ wout,
                                                short* __restrict__ wqt,
                                                short* __restrict__ wot) {
  int i = blockIdx.x * 256 + threadIdx.x;
  if (i < 98304) {
    int n = i >> 8, k = i & 255;
    wqt[i] = f2bf(wqkv[(size_t)k * NQKV + n]);
  }
  if (i < 32768) {
    int c = i >> 7, k = i & 127;
    wot[i] = f2bf(wout[(size_t)k * NC + c]);
  }
}

// ---------------- K1: qkv = x @ w_qkv via MFMA, LDS-staged A, fused k-softmax, bf16 out ----------------
__global__ __launch_bounds__(512) void k_gemm_qkv(const float* __restrict__ x,
                                                  const short* __restrict__ wqt,
                                                  short* __restrict__ qt,
                                                  short* __restrict__ kt,
                                                  short* __restrict__ vt) {
  __shared__ short As[64 * PADA];     // 33792 B; reused as Ks f32[64][132] after K-loop
  float* Ks = (float*)As;

  const int t = threadIdx.x;
  const int lane = t & 63;
  const int w = t >> 6;               // 0..7
  const int l15 = lane & 15;
  const int q = lane >> 4;            // 0..3
  const int h = w >> 2;               // m-half
  const int strip = (w & 3) * 96;
  const int rowBase = blockIdx.x * 64;
  const int b = rowBase >> 12;
  const int d = (rowBase >> 6) & 63;

  // stage x -> bf16 into LDS
  {
    const int r = w;
    const int c = (t & 63) * 4;
#pragma unroll
    for (int it = 0; it < 8; ++it) {
      int row = it * 8 + r;
      float4 f = *(const float4*)(x + (size_t)(rowBase + row) * NC + c);
      s16x4 sv;
      sv[0] = f2bf(f.x); sv[1] = f2bf(f.y); sv[2] = f2bf(f.z); sv[3] = f2bf(f.w);
      *(s16x4*)(As + row * PADA + c) = sv;
    }
  }
  __syncthreads();

  f32x4 acc[2][6] = {};
  for (int ks = 0; ks < 8; ++ks) {
    const int k0 = ks * 32 + q * 8;
    bf16x8 afr[2];
#pragma unroll
    for (int mi = 0; mi < 2; ++mi)
      afr[mi] = *(const bf16x8*)(As + (h * 32 + mi * 16 + l15) * PADA + k0);
#pragma unroll
    for (int nj = 0; nj < 6; ++nj) {
      const int n = strip + nj * 16 + l15;
      bf16x8 bfr = *(const bf16x8*)(wqt + (size_t)n * 256 + k0);
#pragma unroll
      for (int mi = 0; mi < 2; ++mi)
        acc[mi][nj] = __builtin_amdgcn_mfma_f32_16x16x32_bf16(afr[mi], bfr, acc[mi][nj], 0, 0, 0);
    }
  }
  __syncthreads();  // all As reads complete before Ks overwrite

  // epilogue: q,v -> global bf16; k -> LDS fp32 for fused softmax
#pragma unroll
  for (int mi = 0; mi < 2; ++mi) {
#pragma unroll
    for (int nj = 0; nj < 6; ++nj) {
      const int g = strip + nj * 16 + l15;
      const int n_sp = h * 32 + mi * 16 + q * 4;
      if (g < 128) {
        s16x4 sv;
        sv[0] = f2bf(acc[mi][nj][0]); sv[1] = f2bf(acc[mi][nj][1]);
        sv[2] = f2bf(acc[mi][nj][2]); sv[3] = f2bf(acc[mi][nj][3]);
        *(s16x4*)(qt + (((size_t)(b * 128 + g)) << 12) + (d << 6) + n_sp) = sv;
      } else if (g < 256) {
        const int kc = g - 128;
#pragma unroll
        for (int rg = 0; rg < 4; ++rg)
          Ks[(n_sp + rg) * 132 + kc] = acc[mi][nj][rg];
      } else {
        s16x4 sv;
        sv[0] = f2bf(acc[mi][nj][0]); sv[1] = f2bf(acc[mi][nj][1]);
        sv[2] = f2bf(acc[mi][nj][2]); sv[3] = f2bf(acc[mi][nj][3]);
        *(s16x4*)(vt + (((size_t)(b * 128 + (g - 256))) << 12) + (d << 6) + n_sp) = sv;
      }
    }
  }
  __syncthreads();

  // fused k-softmax over the 128-channel axis, one row per 8-lane group
  {
    const int r = t >> 3;
    const int c0 = (t & 7) * 16;
    float vals[16];
    float m = -1e30f;
#pragma unroll
    for (int i = 0; i < 16; ++i) {
      vals[i] = Ks[r * 132 + c0 + i];
      m = fmaxf(m, vals[i]);
    }
    m = fmaxf(m, __shfl_xor(m, 1, 64));
    m = fmaxf(m, __shfl_xor(m, 2, 64));
    m = fmaxf(m, __shfl_xor(m, 4, 64));
    float s = 0.f;
#pragma unroll
    for (int i = 0; i < 16; ++i) {
      vals[i] = __expf(vals[i] - m);
      s += vals[i];
    }
    s += __shfl_xor(s, 1, 64);
    s += __shfl_xor(s, 2, 64);
    s += __shfl_xor(s, 4, 64);
    const float rinv = 1.f / s;
#pragma unroll
    for (int i = 0; i < 16; ++i)
      Ks[r * 132 + c0 + i] = vals[i] * rinv;
  }
  __syncthreads();

  // coalesced copy-out of normalized k as bf16
  {
    const int n = t & 63;
    const int c0 = (t >> 6) * 16;
    const size_t obase = (((size_t)(b * 128)) << 12) + (d << 6) + n;
#pragma unroll
    for (int i = 0; i < 16; ++i)
      kt[obase + (((size_t)(c0 + i)) << 12)] = f2bf(Ks[n * 132 + c0 + i]);
  }
}

// ---------------- K3: per (b,ch): ctx = K V^T ; out^T = P^T ctx via MFMA, bf16 throughout ----------------
// LDS tiles [64][64] bf16, 16B-unit XOR swizzle: phys_unit = unit ^ (row & 7)
__global__ __launch_bounds__(256) void k_attn(const short* __restrict__ kt,
                                              const short* __restrict__ vt,
                                              const short* __restrict__ qt,
                                              short* __restrict__ at) {
  __shared__ short SK[4096];  // K[d][n]
  __shared__ short SV[4096];  // V[e][n]
  __shared__ short SC[4096];  // ctx^T as [e][d]
  __shared__ short SP[4096];  // P^T as [n][d] (softmax(q)*scale, transposed)
  const int ch = blockIdx.x;
  const int b = blockIdx.y;
  const int t = threadIdx.x;
  const int lane = t & 63;
  const int w = t >> 6;       // wave 0..3
  const int l15 = lane & 15;
  const int q = lane >> 4;
  const size_t base = ((size_t)(b * 128 + ch)) << 12;

  // stage K,V -> LDS (swizzled); fully coalesced 32B/thread
  {
    const int row = t >> 2;
    const int u0 = (t & 3) * 2;
    const int src = row * 64 + u0 * 8;
    bf16x8 k0 = *(const bf16x8*)(kt + base + src);
    bf16x8 k1 = *(const bf16x8*)(kt + base + src + 8);
    bf16x8 v0 = *(const bf16x8*)(vt + base + src);
    bf16x8 v1 = *(const bf16x8*)(vt + base + src + 8);
    const int r7 = row & 7;
    *(bf16x8*)(SK + row * 64 + ((u0 ^ r7) << 3)) = k0;
    *(bf16x8*)(SK + row * 64 + (((u0 + 1) ^ r7) << 3)) = k1;
    *(bf16x8*)(SV + row * 64 + ((u0 ^ r7) << 3)) = v0;
    *(bf16x8*)(SV + row * 64 + (((u0 + 1) ^ r7) << 3)) = v1;
  }
  // q softmax over n (W axis), write P^T[n][d] to LDS
  {
    const int dd = t >> 2;
    const int c0 = (t & 3) * 16;
    bf16x8 q0 = *(const bf16x8*)(qt + base + dd * 64 + c0);
    bf16x8 q1 = *(const bf16x8*)(qt + base + dd * 64 + c0 + 8);
    float vals[16];
#pragma unroll
    for (int i = 0; i < 8; ++i) { vals[i] = bf2f(q0[i]); vals[8 + i] = bf2f(q1[i]); }
    float m = -1e30f;
#pragma unroll
    for (int i = 0; i < 16; ++i) m = fmaxf(m, vals[i]);
    m = fmaxf(m, __shfl_xor(m, 1, 64));
    m = fmaxf(m, __shfl_xor(m, 2, 64));
    float s = 0.f;
#pragma unroll
    for (int i = 0; i < 16; ++i) {
      vals[i] = __expf(vals[i] - m);
      s += vals[i];
    }
    s += __shfl_xor(s, 1, 64);
    s += __shfl_xor(s, 2, 64);
    const float r = SMSCALE / s;
    const int du = dd >> 3, doff = dd & 7;
#pragma unroll
    for (int i = 0; i < 16; ++i) {
      const int n = c0 + i;
      SP[n * 64 + ((du ^ (n & 7)) << 3) + doff] = f2bf(vals[i] * r);
    }
  }
  __syncthreads();

  // GEMM1: ctx[d][e] = sum_n K[d][n] V[e][n]; wave w owns d-strip w*16..
  f32x4 acc[4] = {};
#pragma unroll
  for (int ks = 0; ks < 2; ++ks) {
    const int rA = w * 16 + l15;
    bf16x8 afr = *(const bf16x8*)(SK + rA * 64 + (((ks * 4 + q) ^ (rA & 7)) << 3));
#pragma unroll
    for (int nj = 0; nj < 4; ++nj) {
      const int rB = nj * 16 + l15;
      bf16x8 bfr = *(const bf16x8*)(SV + rB * 64 + (((ks * 4 + q) ^ (rB & 7)) << 3));
      acc[nj] = __builtin_amdgcn_mfma_f32_16x16x32_bf16(afr, bfr, acc[nj], 0, 0, 0);
    }
  }
  // write ctx^T[e][d] bf16 (swizzled): lane holds col e=l15, rows d = w*16+q*4+rg
#pragma unroll
  for (int nj = 0; nj < 4; ++nj) {
    const int e = nj * 16 + l15;
    const int d0 = w * 16 + q * 4;
    s16x4 sv;
    sv[0] = f2bf(acc[nj][0]); sv[1] = f2bf(acc[nj][1]);
    sv[2] = f2bf(acc[nj][2]); sv[3] = f2bf(acc[nj][3]);
    *(s16x4*)(SC + e * 64 + (((d0 >> 3) ^ (e & 7)) << 3) + (d0 & 7)) = sv;
  }
  __syncthreads();

  // GEMM2: out^T[n][e] = sum_d P^T[n][d] ctx[d][e]; wave w owns n-strip w*16..
  f32x4 acc2[4] = {};
#pragma unroll
  for (int ks = 0; ks < 2; ++ks) {
    const int rA = w * 16 + l15;   // n row
    bf16x8 afr = *(const bf16x8*)(SP + rA * 64 + (((ks * 4 + q) ^ (rA & 7)) << 3));
#pragma unroll
    for (int nj = 0; nj < 4; ++nj) {
      const int rB = nj * 16 + l15;  // e row of ctx^T
      bf16x8 bfr = *(const bf16x8*)(SC + rB * 64 + (((ks * 4 + q) ^ (rB & 7)) << 3));
      acc2[nj] = __builtin_amdgcn_mfma_f32_16x16x32_bf16(afr, bfr, acc2[nj], 0, 0, 0);
    }
  }
  // store at[e][n] bf16: lane holds col e=l15, rows n = w*16+q*4+rg (contiguous)
#pragma unroll
  for (int nj = 0; nj < 4; ++nj) {
    const int e = nj * 16 + l15;
    const int n0 = w * 16 + q * 4;
    s16x4 sv;
    sv[0] = f2bf(acc2[nj][0]); sv[1] = f2bf(acc2[nj][1]);
    sv[2] = f2bf(acc2[nj][2]); sv[3] = f2bf(acc2[nj][3]);
    *(s16x4*)(at + base + e * 64 + n0) = sv;
  }
}

// ---------------- K4: y = attn @ w_out + b_out via MFMA (bf16 at, XOR-swizzled LDS transpose) ----------------
__global__ __launch_bounds__(256) void k_gemm_out(const short* __restrict__ at,
                                                  const short* __restrict__ wot,
                                                  const float* __restrict__ bias,
                                                  float* __restrict__ y,
                                                  float* __restrict__ sums) {
  __shared__ short As[64 * 128];  // [m=r][k=ch], 16B-unit XOR swizzle: u_phys = u ^ (m&15)
  __shared__ float red[8];
  const int t = threadIdx.x;
  const int lane = t & 63;
  const int w = t >> 6;
  const int l15 = lane & 15;
  const int q = lane >> 4;
  const int rowBase = blockIdx.x * 64;
  const int b = rowBase >> 12;
  const int r0 = rowBase & 4095;
  const size_t abase = (((size_t)(b * 128)) << 12) + r0;
  // stage at[ch][r] (bf16) -> As[r][ch] via 4x4 in-register transpose
  {
    const int tr = t & 15;
    const int tk = t >> 4;
#pragma unroll
    for (int i = 0; i < 2; ++i) {
      const int kq = tk + 16 * i;
      s16x4 f[4];
#pragma unroll
      for (int kc = 0; kc < 4; ++kc)
        f[kc] = *(const s16x4*)(at + abase + (((size_t)(kq * 4 + kc)) << 12) + tr * 4);
      const int ul = kq >> 1, h = kq & 1;
#pragma unroll
      for (int j = 0; j < 4; ++j) {
        int m = tr * 4 + j;
        s16x4 sv;
        sv[0] = f[0][j]; sv[1] = f[1][j]; sv[2] = f[2][j]; sv[3] = f[3][j];
        *(s16x4*)(As + m * 128 + ((ul ^ (m & 15)) << 3) + h * 4) = sv;
      }
    }
  }
  __syncthreads();
  f32x4 acc[4][4] = {};
  for (int ks = 0; ks < 4; ++ks) {
    bf16x8 afr[4];
#pragma unroll
    for (int mi = 0; mi < 4; ++mi) {
      int m = mi * 16 + l15;
      int ul = ks * 4 + q;
      afr[mi] = *(const bf16x8*)(As + m * 128 + ((ul ^ (m & 15)) << 3));
    }
#pragma unroll
    for (int nj = 0; nj < 4; ++nj) {
      int c = w * 64 + nj * 16 + l15;
      bf16x8 bfr = *(const bf16x8*)(wot + (size_t)c * 128 + ks * 32 + q * 8);
#pragma unroll
      for (int mi = 0; mi < 4; ++mi)
        acc[mi][nj] = __builtin_amdgcn_mfma_f32_16x16x32_bf16(afr[mi], bfr, acc[mi][nj], 0, 0, 0);
    }
  }
  // epilogue: bias, store, fused GN partial sums
  float ls = 0.f, lss = 0.f;
#pragma unroll
  for (int mi = 0; mi < 4; ++mi) {
    int r = rowBase + mi * 16 + q * 4;
#pragma unroll
    for (int nj = 0; nj < 4; ++nj) {
      int c = w * 64 + nj * 16 + l15;
      float bv = bias[c];
#pragma unroll
      for (int rg = 0; rg < 4; ++rg) {
        float v = acc[mi][nj][rg] + bv;
        y[(size_t)(r + rg) * NC + c] = v;
        ls += v;
        lss += v * v;
      }
    }
  }
#pragma unroll
  for (int off = 32; off; off >>= 1) {
    ls += __shfl_xor(ls, off, 64);
    lss += __shfl_xor(lss, off, 64);
  }
  if (lane == 0) {
    red[w] = ls;
    red[4 + w] = lss;
  }
  __syncthreads();
  if (t == 0) {
    float S = red[0] + red[1] + red[2] + red[3];
    float SS = red[4] + red[5] + red[6] + red[7];
    atomicAdd(&sums[2 * b], S);
    atomicAdd(&sums[2 * b + 1], SS);
  }
}

// ---------------- K5: GroupNorm(1 group) finalize, in place ----------------
__global__ __launch_bounds__(256) void k_gnorm(float* __restrict__ y,
                                               const float* __restrict__ sums,
                                               const float* __restrict__ gs,
                                               const float* __restrict__ gb) {
  size_t i0 = ((size_t)blockIdx.x * 256 + threadIdx.x) * 4;
  int b = (int)(i0 >> 20);
  int c = (int)(i0 & 255);
  const float invN = 1.0f / 1048576.0f;
  float mean = sums[2 * b] * invN;
  float var = sums[2 * b + 1] * invN - mean * mean;
  float inv = rsqrtf(var + 1e-6f);
  float4 v = *((const float4*)(y + i0));
  float4 g = *((const float4*)(gs + c));
  float4 bb = *((const float4*)(gb + c));
  float4 r;
  r.x = (v.x - mean) * inv * g.x + bb.x;
  r.y = (v.y - mean) * inv * g.y + bb.y;
  r.z = (v.z - mean) * inv * g.z + bb.z;
  r.w = (v.w - mean) * inv * g.w + bb.w;
  *((float4*)(y + i0)) = r;
}

extern "C" void kernel_launch(void* const* d_in, const int* in_sizes, int n_in,
                              void* d_out, int out_size, void* d_ws, size_t ws_size,
                              hipStream_t stream) {
  const float* x = (const float*)d_in[0];
  const float* w_qkv = (const float*)d_in[1];
  const float* w_out = (const float*)d_in[2];
  const float* b_out = (const float*)d_in[3];
  const float* gn_scale = (const float*)d_in[4];
  const float* gn_bias = (const float*)d_in[5];
  float* out = (float*)d_out;

  char* ws = (char*)d_ws;
  const size_t SLAB = (size_t)67108864;  // 64 MiB (bf16 slabs use half)
  short* qt = (short*)ws;
  short* kt = (short*)(ws + SLAB);
  short* vt = (short*)(ws + 2 * SLAB);
  short* at = qt;  // alias: k_attn consumes its qt slice before writing its at slice
  float* sums = (float*)(ws + 3 * SLAB);
  short* wqt = (short*)(ws + 3 * SLAB + 1024);
  short* wot = (short*)(ws + 3 * SLAB + 1024 + 196608);

  hipMemsetAsync(sums, 0, 64 * sizeof(float), stream);

  k_prep_w<<<384, 256, 0, stream>>>(w_qkv, w_out, wqt, wot);
  k_gemm_qkv<<<2048, 512, 0, stream>>>(x, wqt, qt, kt, vt);
  k_attn<<<dim3(128, 32), 256, 0, stream>>>(kt, vt, qt, at);
  k_gemm_out<<<2048, 256, 0, stream>>>(at, wot, b_out, out, sums);
  k_gnorm<<<32768, 256, 0, stream>>>(out, sums, gn_scale, gn_bias);
}

// Round 3
// 379.509 us; speedup vs baseline: 1.4328x; 1.1326x over previous
//
#include <hip/hip_runtime.h>
#include <hip/hip_bf16.h>

typedef __hip_bfloat16 bf16;
typedef float f32x4 __attribute__((ext_vector_type(4)));
typedef short bf16x8 __attribute__((ext_vector_type(8)));
typedef short s16x4 __attribute__((ext_vector_type(4)));

#define NB 32
#define NC 256
#define NHID 128
#define NQKV 384
#define SMSCALE 0.17677669529663687f  // 32^-0.5
#define PADA 264                      // shorts per LDS A-row (256 + 8 pad)

// fp32 -> bf16 round-to-nearest-even (finite inputs)
__device__ __forceinline__ short f2bf(float f) {
  union { float f; unsigned u; } v;
  v.f = f;
  return (short)((v.u + 0x7fffu + ((v.u >> 16) & 1u)) >> 16);
}
__device__ __forceinline__ float bf2f(short s) {
  union { unsigned u; float f; } v;
  v.u = ((unsigned)(unsigned short)s) << 16;
  return v.f;
}

// ---------------- K0: weight prep -> FRAGMENT-READY bf16 layouts ----------------
// wqt: frag index (((s*8+ks)*6+nj)*64+lane)*8+e ; n = s*96+nj*16+(lane&15), k = ks*32+(lane>>4)*8+e
// wot: frag index (((w*4+ks)*4+nj)*64+lane)*8+e ; c = w*64+nj*16+(lane&15), k = ks*32+(lane>>4)*8+e
__global__ __launch_bounds__(256) void k_prep_w(const float* __restrict__ wqkv,
                                                const float* __restrict__ wout,
                                                short* __restrict__ wqt,
                                                short* __restrict__ wot) {
  int i = blockIdx.x * 256 + threadIdx.x;
  if (i < 98304) {
    int e = i & 7, l = (i >> 3) & 63, f = i >> 9;   // f = (s*8+ks)*6+nj
    int nj = f % 6, g = f / 6;
    int ks = g & 7, s = g >> 3;
    int n = s * 96 + nj * 16 + (l & 15);
    int k = ks * 32 + (l >> 4) * 8 + e;
    wqt[i] = f2bf(wqkv[(size_t)k * NQKV + n]);
  }
  if (i < 32768) {
    int e = i & 7, l = (i >> 3) & 63, f = i >> 9;   // f = (w*4+ks)*4+nj
    int nj = f & 3, g = f >> 2;
    int ks = g & 3, w = g >> 2;
    int c = w * 64 + nj * 16 + (l & 15);
    int k = ks * 32 + (l >> 4) * 8 + e;
    wot[i] = f2bf(wout[(size_t)k * NC + c]);
  }
}

// ---------------- K1: qkv = x @ w_qkv via MFMA, LDS-staged A, fused k-softmax, bf16 out ----------------
__global__ __launch_bounds__(512) void k_gemm_qkv(const float* __restrict__ x,
                                                  const short* __restrict__ wqt,
                                                  short* __restrict__ qt,
                                                  short* __restrict__ kt,
                                                  short* __restrict__ vt) {
  __shared__ short As[64 * PADA];     // 33792 B; reused as Ks f32[64][132] after K-loop
  float* Ks = (float*)As;

  const int t = threadIdx.x;
  const int lane = t & 63;
  const int w = t >> 6;               // 0..7
  const int l15 = lane & 15;
  const int q = lane >> 4;            // 0..3
  const int h = w >> 2;               // m-half
  const int strip = (w & 3) * 96;
  const int rowBase = blockIdx.x * 64;
  const int b = rowBase >> 12;
  const int d = (rowBase >> 6) & 63;

  // stage x -> bf16 into LDS
  {
    const int r = w;
    const int c = (t & 63) * 4;
#pragma unroll
    for (int it = 0; it < 8; ++it) {
      int row = it * 8 + r;
      float4 f = *(const float4*)(x + (size_t)(rowBase + row) * NC + c);
      s16x4 sv;
      sv[0] = f2bf(f.x); sv[1] = f2bf(f.y); sv[2] = f2bf(f.z); sv[3] = f2bf(f.w);
      *(s16x4*)(As + row * PADA + c) = sv;
    }
  }
  __syncthreads();

  // fragment-ready B base for this wave's strip: fully-coalesced 1KB wave-loads
  const short* wqb = wqt + (((size_t)(w & 3) * 8) * 6) * 512 + lane * 8;

  f32x4 acc[2][6] = {};
  for (int ks = 0; ks < 8; ++ks) {
    const int k0 = ks * 32 + q * 8;
    bf16x8 afr[2];
#pragma unroll
    for (int mi = 0; mi < 2; ++mi)
      afr[mi] = *(const bf16x8*)(As + (h * 32 + mi * 16 + l15) * PADA + k0);
#pragma unroll
    for (int nj = 0; nj < 6; ++nj) {
      bf16x8 bfr = *(const bf16x8*)(wqb + (ks * 6 + nj) * 512);
#pragma unroll
      for (int mi = 0; mi < 2; ++mi)
        acc[mi][nj] = __builtin_amdgcn_mfma_f32_16x16x32_bf16(afr[mi], bfr, acc[mi][nj], 0, 0, 0);
    }
  }
  __syncthreads();  // all As reads complete before Ks overwrite

  // epilogue: q,v -> global bf16; k -> LDS fp32 for fused softmax
#pragma unroll
  for (int mi = 0; mi < 2; ++mi) {
#pragma unroll
    for (int nj = 0; nj < 6; ++nj) {
      const int g = strip + nj * 16 + l15;
      const int n_sp = h * 32 + mi * 16 + q * 4;
      if (g < 128) {
        s16x4 sv;
        sv[0] = f2bf(acc[mi][nj][0]); sv[1] = f2bf(acc[mi][nj][1]);
        sv[2] = f2bf(acc[mi][nj][2]); sv[3] = f2bf(acc[mi][nj][3]);
        *(s16x4*)(qt + (((size_t)(b * 128 + g)) << 12) + (d << 6) + n_sp) = sv;
      } else if (g < 256) {
        const int kc = g - 128;
#pragma unroll
        for (int rg = 0; rg < 4; ++rg)
          Ks[(n_sp + rg) * 132 + kc] = acc[mi][nj][rg];
      } else {
        s16x4 sv;
        sv[0] = f2bf(acc[mi][nj][0]); sv[1] = f2bf(acc[mi][nj][1]);
        sv[2] = f2bf(acc[mi][nj][2]); sv[3] = f2bf(acc[mi][nj][3]);
        *(s16x4*)(vt + (((size_t)(b * 128 + (g - 256))) << 12) + (d << 6) + n_sp) = sv;
      }
    }
  }
  __syncthreads();

  // fused k-softmax over the 128-channel axis, one row per 8-lane group
  {
    const int r = t >> 3;
    const int c0 = (t & 7) * 16;
    float vals[16];
    float m = -1e30f;
#pragma unroll
    for (int i = 0; i < 16; ++i) {
      vals[i] = Ks[r * 132 + c0 + i];
      m = fmaxf(m, vals[i]);
    }
    m = fmaxf(m, __shfl_xor(m, 1, 64));
    m = fmaxf(m, __shfl_xor(m, 2, 64));
    m = fmaxf(m, __shfl_xor(m, 4, 64));
    float s = 0.f;
#pragma unroll
    for (int i = 0; i < 16; ++i) {
      vals[i] = __expf(vals[i] - m);
      s += vals[i];
    }
    s += __shfl_xor(s, 1, 64);
    s += __shfl_xor(s, 2, 64);
    s += __shfl_xor(s, 4, 64);
    const float rinv = 1.f / s;
#pragma unroll
    for (int i = 0; i < 16; ++i)
      Ks[r * 132 + c0 + i] = vals[i] * rinv;
  }
  __syncthreads();

  // coalesced copy-out of normalized k as bf16
  {
    const int n = t & 63;
    const int c0 = (t >> 6) * 16;
    const size_t obase = (((size_t)(b * 128)) << 12) + (d << 6) + n;
#pragma unroll
    for (int i = 0; i < 16; ++i)
      kt[obase + (((size_t)(c0 + i)) << 12)] = f2bf(Ks[n * 132 + c0 + i]);
  }
}

// ---------------- K3: per (b,ch): ctx = K V^T ; out^T = P^T ctx via MFMA, bf16 throughout ----------------
__global__ __launch_bounds__(256) void k_attn(const short* __restrict__ kt,
                                              const short* __restrict__ vt,
                                              const short* __restrict__ qt,
                                              short* __restrict__ at) {
  __shared__ short SK[4096];  // K[d][n]
  __shared__ short SV[4096];  // V[e][n]
  __shared__ short SC[4096];  // ctx^T as [e][d]
  __shared__ short SP[4096];  // P^T as [n][d]
  const int ch = blockIdx.x;
  const int b = blockIdx.y;
  const int t = threadIdx.x;
  const int lane = t & 63;
  const int w = t >> 6;
  const int l15 = lane & 15;
  const int q = lane >> 4;
  const size_t base = ((size_t)(b * 128 + ch)) << 12;

  {
    const int row = t >> 2;
    const int u0 = (t & 3) * 2;
    const int src = row * 64 + u0 * 8;
    bf16x8 k0 = *(const bf16x8*)(kt + base + src);
    bf16x8 k1 = *(const bf16x8*)(kt + base + src + 8);
    bf16x8 v0 = *(const bf16x8*)(vt + base + src);
    bf16x8 v1 = *(const bf16x8*)(vt + base + src + 8);
    const int r7 = row & 7;
    *(bf16x8*)(SK + row * 64 + ((u0 ^ r7) << 3)) = k0;
    *(bf16x8*)(SK + row * 64 + (((u0 + 1) ^ r7) << 3)) = k1;
    *(bf16x8*)(SV + row * 64 + ((u0 ^ r7) << 3)) = v0;
    *(bf16x8*)(SV + row * 64 + (((u0 + 1) ^ r7) << 3)) = v1;
  }
  {
    const int dd = t >> 2;
    const int c0 = (t & 3) * 16;
    bf16x8 q0 = *(const bf16x8*)(qt + base + dd * 64 + c0);
    bf16x8 q1 = *(const bf16x8*)(qt + base + dd * 64 + c0 + 8);
    float vals[16];
#pragma unroll
    for (int i = 0; i < 8; ++i) { vals[i] = bf2f(q0[i]); vals[8 + i] = bf2f(q1[i]); }
    float m = -1e30f;
#pragma unroll
    for (int i = 0; i < 16; ++i) m = fmaxf(m, vals[i]);
    m = fmaxf(m, __shfl_xor(m, 1, 64));
    m = fmaxf(m, __shfl_xor(m, 2, 64));
    float s = 0.f;
#pragma unroll
    for (int i = 0; i < 16; ++i) {
      vals[i] = __expf(vals[i] - m);
      s += vals[i];
    }
    s += __shfl_xor(s, 1, 64);
    s += __shfl_xor(s, 2, 64);
    const float r = SMSCALE / s;
    const int du = dd >> 3, doff = dd & 7;
#pragma unroll
    for (int i = 0; i < 16; ++i) {
      const int n = c0 + i;
      SP[n * 64 + ((du ^ (n & 7)) << 3) + doff] = f2bf(vals[i] * r);
    }
  }
  __syncthreads();

  f32x4 acc[4] = {};
#pragma unroll
  for (int ks = 0; ks < 2; ++ks) {
    const int rA = w * 16 + l15;
    bf16x8 afr = *(const bf16x8*)(SK + rA * 64 + (((ks * 4 + q) ^ (rA & 7)) << 3));
#pragma unroll
    for (int nj = 0; nj < 4; ++nj) {
      const int rB = nj * 16 + l15;
      bf16x8 bfr = *(const bf16x8*)(SV + rB * 64 + (((ks * 4 + q) ^ (rB & 7)) << 3));
      acc[nj] = __builtin_amdgcn_mfma_f32_16x16x32_bf16(afr, bfr, acc[nj], 0, 0, 0);
    }
  }
#pragma unroll
  for (int nj = 0; nj < 4; ++nj) {
    const int e = nj * 16 + l15;
    const int d0 = w * 16 + q * 4;
    s16x4 sv;
    sv[0] = f2bf(acc[nj][0]); sv[1] = f2bf(acc[nj][1]);
    sv[2] = f2bf(acc[nj][2]); sv[3] = f2bf(acc[nj][3]);
    *(s16x4*)(SC + e * 64 + (((d0 >> 3) ^ (e & 7)) << 3) + (d0 & 7)) = sv;
  }
  __syncthreads();

  f32x4 acc2[4] = {};
#pragma unroll
  for (int ks = 0; ks < 2; ++ks) {
    const int rA = w * 16 + l15;
    bf16x8 afr = *(const bf16x8*)(SP + rA * 64 + (((ks * 4 + q) ^ (rA & 7)) << 3));
#pragma unroll
    for (int nj = 0; nj < 4; ++nj) {
      const int rB = nj * 16 + l15;
      bf16x8 bfr = *(const bf16x8*)(SC + rB * 64 + (((ks * 4 + q) ^ (rB & 7)) << 3));
      acc2[nj] = __builtin_amdgcn_mfma_f32_16x16x32_bf16(afr, bfr, acc2[nj], 0, 0, 0);
    }
  }
#pragma unroll
  for (int nj = 0; nj < 4; ++nj) {
    const int e = nj * 16 + l15;
    const int n0 = w * 16 + q * 4;
    s16x4 sv;
    sv[0] = f2bf(acc2[nj][0]); sv[1] = f2bf(acc2[nj][1]);
    sv[2] = f2bf(acc2[nj][2]); sv[3] = f2bf(acc2[nj][3]);
    *(s16x4*)(at + base + e * 64 + n0) = sv;
  }
}

// ---------------- K4: y = attn @ w_out + b_out via MFMA (frag-ready wot) ----------------
__global__ __launch_bounds__(256) void k_gemm_out(const short* __restrict__ at,
                                                  const short* __restrict__ wot,
                                                  const float* __restrict__ bias,
                                                  float* __restrict__ y,
                                                  float* __restrict__ sums) {
  __shared__ short As[64 * 128];  // [m=r][k=ch], 16B-unit XOR swizzle: u_phys = u ^ (m&15)
  __shared__ float red[8];
  const int t = threadIdx.x;
  const int lane = t & 63;
  const int w = t >> 6;
  const int l15 = lane & 15;
  const int q = lane >> 4;
  const int rowBase = blockIdx.x * 64;
  const int b = rowBase >> 12;
  const int r0 = rowBase & 4095;
  const size_t abase = (((size_t)(b * 128)) << 12) + r0;
  {
    const int tr = t & 15;
    const int tk = t >> 4;
#pragma unroll
    for (int i = 0; i < 2; ++i) {
      const int kq = tk + 16 * i;
      s16x4 f[4];
#pragma unroll
      for (int kc = 0; kc < 4; ++kc)
        f[kc] = *(const s16x4*)(at + abase + (((size_t)(kq * 4 + kc)) << 12) + tr * 4);
      const int ul = kq >> 1, hh = kq & 1;
#pragma unroll
      for (int j = 0; j < 4; ++j) {
        int m = tr * 4 + j;
        s16x4 sv;
        sv[0] = f[0][j]; sv[1] = f[1][j]; sv[2] = f[2][j]; sv[3] = f[3][j];
        *(s16x4*)(As + m * 128 + ((ul ^ (m & 15)) << 3) + hh * 4) = sv;
      }
    }
  }
  __syncthreads();
  const short* wob = wot + ((size_t)(w * 4) * 4) * 512 + lane * 8;
  f32x4 acc[4][4] = {};
  for (int ks = 0; ks < 4; ++ks) {
    bf16x8 afr[4];
#pragma unroll
    for (int mi = 0; mi < 4; ++mi) {
      int m = mi * 16 + l15;
      int ul = ks * 4 + q;
      afr[mi] = *(const bf16x8*)(As + m * 128 + ((ul ^ (m & 15)) << 3));
    }
#pragma unroll
    for (int nj = 0; nj < 4; ++nj) {
      bf16x8 bfr = *(const bf16x8*)(wob + (ks * 4 + nj) * 512);
#pragma unroll
      for (int mi = 0; mi < 4; ++mi)
        acc[mi][nj] = __builtin_amdgcn_mfma_f32_16x16x32_bf16(afr[mi], bfr, acc[mi][nj], 0, 0, 0);
    }
  }
  float ls = 0.f, lss = 0.f;
#pragma unroll
  for (int mi = 0; mi < 4; ++mi) {
    int r = rowBase + mi * 16 + q * 4;
#pragma unroll
    for (int nj = 0; nj < 4; ++nj) {
      int c = w * 64 + nj * 16 + l15;
      float bv = bias[c];
#pragma unroll
      for (int rg = 0; rg < 4; ++rg) {
        float v = acc[mi][nj][rg] + bv;
        y[(size_t)(r + rg) * NC + c] = v;
        ls += v;
        lss += v * v;
      }
    }
  }
#pragma unroll
  for (int off = 32; off; off >>= 1) {
    ls += __shfl_xor(ls, off, 64);
    lss += __shfl_xor(lss, off, 64);
  }
  if (lane == 0) {
    red[w] = ls;
    red[4 + w] = lss;
  }
  __syncthreads();
  if (t == 0) {
    float S = red[0] + red[1] + red[2] + red[3];
    float SS = red[4] + red[5] + red[6] + red[7];
    atomicAdd(&sums[2 * b], S);
    atomicAdd(&sums[2 * b + 1], SS);
  }
}

// ---------------- K5: GroupNorm(1 group) finalize, in place ----------------
__global__ __launch_bounds__(256) void k_gnorm(float* __restrict__ y,
                                               const float* __restrict__ sums,
                                               const float* __restrict__ gs,
                                               const float* __restrict__ gb) {
  size_t i0 = ((size_t)blockIdx.x * 256 + threadIdx.x) * 4;
  int b = (int)(i0 >> 20);
  int c = (int)(i0 & 255);
  const float invN = 1.0f / 1048576.0f;
  float mean = sums[2 * b] * invN;
  float var = sums[2 * b + 1] * invN - mean * mean;
  float inv = rsqrtf(var + 1e-6f);
  float4 v = *((const float4*)(y + i0));
  float4 g = *((const float4*)(gs + c));
  float4 bb = *((const float4*)(gb + c));
  float4 r;
  r.x = (v.x - mean) * inv * g.x + bb.x;
  r.y = (v.y - mean) * inv * g.y + bb.y;
  r.z = (v.z - mean) * inv * g.z + bb.z;
  r.w = (v.w - mean) * inv * g.w + bb.w;
  *((float4*)(y + i0)) = r;
}

extern "C" void kernel_launch(void* const* d_in, const int* in_sizes, int n_in,
                              void* d_out, int out_size, void* d_ws, size_t ws_size,
                              hipStream_t stream) {
  const float* x = (const float*)d_in[0];
  const float* w_qkv = (const float*)d_in[1];
  const float* w_out = (const float*)d_in[2];
  const float* b_out = (const float*)d_in[3];
  const float* gn_scale = (const float*)d_in[4];
  const float* gn_bias = (const float*)d_in[5];
  float* out = (float*)d_out;

  char* ws = (char*)d_ws;
  const size_t SLAB = (size_t)67108864;  // 64 MiB (bf16 slabs use half)
  short* qt = (short*)ws;
  short* kt = (short*)(ws + SLAB);
  short* vt = (short*)(ws + 2 * SLAB);
  short* at = qt;  // alias: k_attn consumes its qt slice before writing its at slice
  float* sums = (float*)(ws + 3 * SLAB);
  short* wqt = (short*)(ws + 3 * SLAB + 1024);
  short* wot = (short*)(ws + 3 * SLAB + 1024 + 196608);

  hipMemsetAsync(sums, 0, 64 * sizeof(float), stream);

  k_prep_w<<<384, 256, 0, stream>>>(w_qkv, w_out, wqt, wot);
  k_gemm_qkv<<<2048, 512, 0, stream>>>(x, wqt, qt, kt, vt);
  k_attn<<<dim3(128, 32), 256, 0, stream>>>(kt, vt, qt, at);
  k_gemm_out<<<2048, 256, 0, stream>>>(at, wot, b_out, out, sums);
  k_gnorm<<<32768, 256, 0, stream>>>(out, sums, gn_scale, gn_bias);
}